// Round 1
// baseline (631.881 us; speedup 1.0000x reference)
//
#include <hip/hip_runtime.h>
#include <cstdint>

// ---------------------------------------------------------------------------
// GConv: out = W @ gelu( ifft(fft(u)*fft(k_norm)) + u*D ) + bias
//   u: (8,1024,4096) f32; k0..k6: (1,1024,64) f32; D: (1,1024); W: (1024,1024); b: (1024,)
// Pipeline:
//   1. prep_kf   : build 4096-tap normalized kernel per d, rfft(8192) -> Kf (complex, /4096)
//   2. wcast     : W f32 -> bf16
//   3. fftconv   : per (b,d) row: rfft(u) * Kf -> irfft, + u*D, gelu -> y bf16 [b][d][l]
//   4. transpose : y -> yT bf16 [(b,l)][d]   (K-contiguous for MFMA B operand)
//   5. gemm      : out[b][v][l] = sum_u Wbf[v][u] * yT[(b,l)][u] + bias[v]  (16x16x32 bf16 MFMA)
// ---------------------------------------------------------------------------

#define TWO_PI 6.283185307179586f

typedef __bf16 bf16;
typedef __bf16 bf16x4 __attribute__((ext_vector_type(4)));
typedef __bf16 bf16x8 __attribute__((ext_vector_type(8)));
typedef float  f32x4  __attribute__((ext_vector_type(4)));

__device__ __forceinline__ float2 cadd(float2 a, float2 b){ return make_float2(a.x+b.x, a.y+b.y); }
__device__ __forceinline__ float2 csub(float2 a, float2 b){ return make_float2(a.x-b.x, a.y-b.y); }
__device__ __forceinline__ float2 cmul(float2 a, float2 b){ return make_float2(a.x*b.x-a.y*b.y, a.x*b.y+a.y*b.x); }

// Radix-4 Stockham FFT, N=4096, 256 threads, ping-pong LDS buffers.
// SIGN=-1 forward (e^-i), SIGN=+1 inverse (e^+i, unnormalized). Result ends in bufA.
template<int SIGN>
__device__ inline void fft4096(float2* bufA, float2* bufB, int tid)
{
  float2* src = bufA;
  float2* dst = bufB;
  #pragma unroll
  for (int s = 0; s < 6; ++s) {
    const int m = 1 << (2*s);
    __syncthreads();
    #pragma unroll
    for (int it = 0; it < 4; ++it) {
      int bid = tid + it*256;        // 1024 butterflies/stage
      int k = bid & (m-1);
      int j = bid >> (2*s);          // j in [0, l), l = 1024>>2s; m*l == 1024
      int rbase = k + m*j;
      float2 c0 = src[rbase];
      float2 c1 = src[rbase + 1024];
      float2 c2 = src[rbase + 2048];
      float2 c3 = src[rbase + 3072];
      float2 t0 = cadd(c0, c2);
      float2 t1 = csub(c0, c2);
      float2 t2 = cadd(c1, c3);
      float2 dd = csub(c1, c3);
      float2 t3 = (SIGN < 0) ? make_float2(dd.y, -dd.x) : make_float2(-dd.y, dd.x);
      float ang = (float)SIGN * (TWO_PI/4096.0f) * (float)(j << (2*s));
      float sn, cs;
      __sincosf(ang, &sn, &cs);
      float2 w1 = make_float2(cs, sn);
      float2 w2 = cmul(w1, w1);
      float2 w3 = cmul(w2, w1);
      int wbase = k + 4*m*j;
      dst[wbase]       = cadd(t0, t2);
      dst[wbase + m]   = cmul(w1, cadd(t1, t3));
      dst[wbase + 2*m] = cmul(w2, csub(t0, t2));
      dst[wbase + 3*m] = cmul(w3, csub(t1, t3));
    }
    float2* tmp = src; src = dst; dst = tmp;
  }
  __syncthreads();
}

// ---------------------------------------------------------------------------
// Kernel 1: build normalized conv kernel per channel d, rfft(8192) via packed
// complex FFT(4096), store Kf[d][j] = X_k[j]/4096 for j=0..4096 (row stride 4104).
// ---------------------------------------------------------------------------
__global__ __launch_bounds__(256) void prep_kf_kernel(
    const float* __restrict__ k0, const float* __restrict__ k1, const float* __restrict__ k2,
    const float* __restrict__ k3, const float* __restrict__ k4, const float* __restrict__ k5,
    const float* __restrict__ k6, float2* __restrict__ Kf)
{
  extern __shared__ __align__(16) float2 smem[];
  float2* bufA = smem;            // 4096 complex
  float2* bufB = smem + 4096;     // 4096 complex
  float*  kk   = (float*)bufB;    // 4096 floats (raw kernel taps)
  float*  red  = (float*)bufA;    // reduction scratch
  int tid = threadIdx.x;
  int d = blockIdx.x;
  const float* kp[7] = { k0 + d*64, k1 + d*64, k2 + d*64, k3 + d*64,
                         k4 + d*64, k5 + d*64, k6 + d*64 };
  // linear interpolation (torch F.interpolate, align_corners=False) per segment
  #pragma unroll
  for (int it = 0; it < 16; ++it) {
    int idx = tid + it*256;
    int seg, s, base;
    if      (idx <   64) { seg=0; s=1;  base=0;    }
    else if (idx <  128) { seg=1; s=1;  base=64;   }
    else if (idx <  256) { seg=2; s=2;  base=128;  }
    else if (idx <  512) { seg=3; s=4;  base=256;  }
    else if (idx < 1024) { seg=4; s=8;  base=512;  }
    else if (idx < 2048) { seg=5; s=16; base=1024; }
    else                 { seg=6; s=32; base=2048; }
    int j = idx - base;
    float coord = ((float)j + 0.5f) / (float)s - 0.5f;
    coord = fminf(fmaxf(coord, 0.0f), 63.0f);
    int lo = (int)coord;                 // coord >= 0 -> trunc == floor
    int hi = min(lo + 1, 63);
    float w = coord - (float)lo;
    const float* kpp = kp[seg];
    kk[idx] = kpp[lo] * (1.0f - w) + kpp[hi] * w;
  }
  __syncthreads();
  float psum = 0.f;
  #pragma unroll
  for (int it = 0; it < 16; ++it) { float v = kk[tid + it*256]; psum += v*v; }
  red[tid] = psum;
  __syncthreads();
  if (tid == 0) {
    float tot = 0.f;
    for (int i = 0; i < 256; ++i) tot += red[i];
    red[0] = 1.0f / sqrtf(tot);
  }
  __syncthreads();
  float inv = red[0];
  __syncthreads();
  // pack z[m] = (k[2m] + i k[2m+1]) * inv  (k zero-padded to 8192)
  #pragma unroll
  for (int it = 0; it < 8; ++it) {
    int m_ = tid + it*256;
    bufA[m_]        = make_float2(kk[2*m_] * inv, kk[2*m_+1] * inv);
    bufA[m_ + 2048] = make_float2(0.f, 0.f);
  }
  fft4096<-1>(bufA, bufB, tid);
  // unpack packed-real FFT -> X_k[0..4096], scaled by 1/4096 (inverse norm folded here)
  const float S = 1.0f/4096.0f;
  float2* kfr = Kf + (size_t)d * 4104;
  for (int j = tid; j < 2048; j += 256) {
    if (j == 0) {
      float2 Z0 = bufA[0];
      kfr[0]    = make_float2((Z0.x + Z0.y) * S, 0.f);
      kfr[4096] = make_float2((Z0.x - Z0.y) * S, 0.f);
      float2 Zh = bufA[2048];
      kfr[2048] = make_float2(Zh.x * S, -Zh.y * S);   // conj(Z[2048])/4096
    } else {
      float2 Zj = bufA[j];
      float2 Zm = bufA[4096 - j];
      float2 E = make_float2(0.5f*(Zj.x + Zm.x), 0.5f*(Zj.y - Zm.y));
      float2 O = make_float2(0.5f*(Zj.y + Zm.y), 0.5f*(Zm.x - Zj.x));
      float ang = -(TWO_PI/8192.0f) * (float)j;
      float sn, cs; __sincosf(ang, &sn, &cs);
      float2 W = make_float2(cs, sn);                  // e^{-2pi i j/8192}
      float2 T = cmul(W, O);
      kfr[j]        = make_float2((E.x + T.x)*S, (E.y + T.y)*S);     // X[j]
      kfr[4096 - j] = make_float2((E.x - T.x)*S, (T.y - E.y)*S);     // conj(E-T)
    }
  }
}

// ---------------------------------------------------------------------------
// Kernel 2: W f32 -> bf16
// ---------------------------------------------------------------------------
__global__ __launch_bounds__(256) void wcast_kernel(const float* __restrict__ W,
                                                    bf16* __restrict__ Wbf)
{
  int i4 = blockIdx.x * 256 + threadIdx.x;     // 262144 float4s
  float4 v = ((const float4*)W)[i4];
  bf16x4 h; h[0] = (bf16)v.x; h[1] = (bf16)v.y; h[2] = (bf16)v.z; h[3] = (bf16)v.w;
  *(bf16x4*)(Wbf + (size_t)i4 * 4) = h;
}

// ---------------------------------------------------------------------------
// Kernel 3: per-(b,d) row FFT convolution, fused D-term + exact GELU -> bf16 y
// blockIdx.x = d*8 + b  (batch-adjacent so Kf row is L2-hot)
// ---------------------------------------------------------------------------
__global__ __launch_bounds__(256) void fftconv_kernel(
    const float* __restrict__ u, const float* __restrict__ Dv,
    const float2* __restrict__ Kf, bf16* __restrict__ ynat)
{
  extern __shared__ __align__(16) float2 smem[];
  float2* bufA = smem;
  float2* bufB = smem + 4096;
  int tid = threadIdx.x;
  int d = blockIdx.x >> 3;
  int b = blockIdx.x & 7;
  int row = b * 1024 + d;
  const float* uRow = u + (size_t)row * 4096;
  const float4* uR4 = (const float4*)uRow;
  // pack z[m] = u[2m] + i u[2m+1], zero-pad upper half
  #pragma unroll
  for (int it = 0; it < 4; ++it) {
    int idx = tid + it*256;
    float4 v = uR4[idx];
    bufA[2*idx]   = make_float2(v.x, v.y);
    bufA[2*idx+1] = make_float2(v.z, v.w);
  }
  #pragma unroll
  for (int it = 0; it < 8; ++it)
    bufA[2048 + tid + it*256] = make_float2(0.f, 0.f);

  fft4096<-1>(bufA, bufB, tid);

  // unpack -> X_u, multiply by Kf -> P, repack -> Q for packed inverse (in-place)
  const float2* kfr = Kf + (size_t)d * 4104;
  for (int j = tid; j < 2048; j += 256) {
    if (j == 0) {
      float2 Z0 = bufA[0];
      float X0 = Z0.x + Z0.y;
      float XM = Z0.x - Z0.y;
      float P0 = X0 * kfr[0].x;
      float PM = XM * kfr[4096].x;
      bufA[0] = make_float2(0.5f*(P0 + PM), 0.5f*(P0 - PM));
      float2 Zh = bufA[2048];
      float2 Xh = make_float2(Zh.x, -Zh.y);            // conj(Z[2048])
      float2 Ph = cmul(Xh, kfr[2048]);
      bufA[2048] = make_float2(Ph.x, -Ph.y);           // conj(P)
    } else {
      float2 Zj = bufA[j];
      float2 Zm = bufA[4096 - j];
      float2 E = make_float2(0.5f*(Zj.x + Zm.x), 0.5f*(Zj.y - Zm.y));
      float2 O = make_float2(0.5f*(Zj.y + Zm.y), 0.5f*(Zm.x - Zj.x));
      float ang = -(TWO_PI/8192.0f) * (float)j;
      float sn, cs; __sincosf(ang, &sn, &cs);
      float2 W = make_float2(cs, sn);                  // e^{-i th}
      float2 T = cmul(W, O);
      float2 Xj = cadd(E, T);                          // X_u[j]
      float2 Xm = make_float2(E.x - T.x, T.y - E.y);   // X_u[M-j] = conj(E-T)
      float2 Pj = cmul(Xj, kfr[j]);
      float2 Pm = cmul(Xm, kfr[4096 - j]);
      float2 Ep = make_float2(0.5f*(Pj.x + Pm.x), 0.5f*(Pj.y - Pm.y)); // (Pj+conj(Pm))/2
      float2 V  = make_float2(0.5f*(Pj.x - Pm.x), 0.5f*(Pj.y + Pm.y)); // (Pj-conj(Pm))/2
      float2 Wi = make_float2(cs, -sn);                // e^{+i th}
      float2 Op = cmul(Wi, V);
      bufA[j]        = make_float2(Ep.x - Op.y, Ep.y + Op.x);  // E' + i O'
      bufA[4096 - j] = make_float2(Ep.x + Op.y, Op.x - Ep.y);  // conj(E') + i conj(O')
    }
  }

  fft4096<1>(bufA, bufB, tid);   // inverse (1/4096 folded into Kf); y interleaved in re/im

  // epilogue: y[n] + u[n]*D, exact gelu, bf16 store (16 contiguous n per thread)
  float Dd = Dv[d];
  float vals[16];
  const float4* qa = (const float4*)(bufA + (size_t)tid * 8);
  #pragma unroll
  for (int i = 0; i < 4; ++i) {
    float4 q = qa[i];
    vals[4*i+0] = q.x; vals[4*i+1] = q.y; vals[4*i+2] = q.z; vals[4*i+3] = q.w;
  }
  #pragma unroll
  for (int i = 0; i < 4; ++i) {
    float4 uu = uR4[tid*4 + i];
    vals[4*i+0] += uu.x * Dd;
    vals[4*i+1] += uu.y * Dd;
    vals[4*i+2] += uu.z * Dd;
    vals[4*i+3] += uu.w * Dd;
  }
  union { bf16 h[16]; uint4 q[2]; } st;
  #pragma unroll
  for (int i = 0; i < 16; ++i) {
    float x = vals[i];
    float g = 0.5f * x * (1.0f + erff(x * 0.70710678118654752440f));
    st.h[i] = (bf16)g;
  }
  uint4* outp = (uint4*)(ynat + (size_t)row * 4096 + tid * 16);
  outp[0] = st.q[0];
  outp[1] = st.q[1];
}

// ---------------------------------------------------------------------------
// Kernel 4: y [b][u][l] bf16 -> yT [(b,l)][u] bf16 (64x64 tiles via LDS)
// ---------------------------------------------------------------------------
__global__ __launch_bounds__(256) void transpose_kernel(const ushort* __restrict__ ynat,
                                                        ushort* __restrict__ yT)
{
  __shared__ ushort T[64 * 68];
  int tid = threadIdx.x;
  int l0 = blockIdx.x * 64;
  int u0 = blockIdx.y * 64;
  int b  = blockIdx.z;
  const ushort* src = ynat + ((size_t)(b*1024 + u0)) * 4096 + l0;
  #pragma unroll
  for (int it = 0; it < 4; ++it) {
    int c = tid + it*256;
    int r = c >> 4;        // u-local
    int c4 = c & 15;       // l chunk of 4
    ushort4 v = *(const ushort4*)(src + (size_t)r * 4096 + c4*4);
    *(ushort4*)&T[r*68 + c4*4] = v;
  }
  __syncthreads();
  ushort* dst = yT + ((size_t)(b*4096 + l0)) * 1024 + u0;
  #pragma unroll
  for (int it = 0; it < 4; ++it) {
    int c = tid + it*256;
    int lr = c >> 4;       // l-local
    int u4 = c & 15;       // u chunk of 4
    ushort4 v;
    v.x = T[(u4*4+0)*68 + lr];
    v.y = T[(u4*4+1)*68 + lr];
    v.z = T[(u4*4+2)*68 + lr];
    v.w = T[(u4*4+3)*68 + lr];
    *(ushort4*)(dst + (size_t)lr * 1024 + u4*4) = v;
  }
}

// ---------------------------------------------------------------------------
// Kernel 5: GEMM out[b][v][l] = sum_u Wbf[v][u] * yT[(b,l)][u] + bias[v]
// M=1024(v), N=32768(b,l), K=1024(u); 128x128 tile, BK=32, 16x16x32 bf16 MFMA
// ---------------------------------------------------------------------------
#define GL_LDS16(g, l) __builtin_amdgcn_global_load_lds( \
    (const __attribute__((address_space(1))) void*)(g),  \
    (__attribute__((address_space(3))) void*)(l), 16, 0, 0)

__global__ __launch_bounds__(256) void gemm_kernel(
    const bf16* __restrict__ A,      // Wbf [v][u] 1024x1024
    const bf16* __restrict__ B,      // yT [(b,l)][u] 32768x1024
    const float* __restrict__ bias,
    float* __restrict__ out)
{
  __shared__ bf16 ldsA[128 * 32];
  __shared__ bf16 ldsB[128 * 32];
  int tid = threadIdx.x;
  int lane = tid & 63;
  int w = tid >> 6;
  int wm = w & 1, wn = w >> 1;
  int m0 = blockIdx.x * 128;
  int n0 = blockIdx.y * 128;
  int lrow = lane & 15;
  int quad = lane >> 4;
  f32x4 acc[4][4] = {};
  for (int kk0 = 0; kk0 < 1024; kk0 += 32) {
    __syncthreads();
    #pragma unroll
    for (int i = 0; i < 2; ++i) {
      int c = tid + 256*i;           // 512 chunks of 16B per tile
      int row = c >> 2;
      int kc = c & 3;
      const bf16* ga = A + (size_t)(m0 + row) * 1024 + kk0 + kc*8;
      bf16* la = ldsA + (size_t)(w*64 + 256*i) * 8;     // wave-uniform base; HW adds lane*16B
      GL_LDS16(ga, la);
      const bf16* gb = B + (size_t)(n0 + row) * 1024 + kk0 + kc*8;
      bf16* lb = ldsB + (size_t)(w*64 + 256*i) * 8;
      GL_LDS16(gb, lb);
    }
    __syncthreads();
    bf16x8 a[4], bq[4];
    #pragma unroll
    for (int mi = 0; mi < 4; ++mi)
      a[mi] = *(const bf16x8*)&ldsA[(wm*64 + mi*16 + lrow)*32 + quad*8];
    #pragma unroll
    for (int ni = 0; ni < 4; ++ni)
      bq[ni] = *(const bf16x8*)&ldsB[(wn*64 + ni*16 + lrow)*32 + quad*8];
    #pragma unroll
    for (int mi = 0; mi < 4; ++mi)
      #pragma unroll
      for (int ni = 0; ni < 4; ++ni)
        acc[mi][ni] = __builtin_amdgcn_mfma_f32_16x16x32_bf16(a[mi], bq[ni], acc[mi][ni], 0, 0, 0);
  }
  // epilogue: D[row=quad*4+r][col=lrow], out idx = (b<<22) + (v<<12) + l
  #pragma unroll
  for (int mi = 0; mi < 4; ++mi) {
    #pragma unroll
    for (int r = 0; r < 4; ++r) {
      int vrow = m0 + wm*64 + mi*16 + quad*4 + r;
      float bv = bias[vrow];
      #pragma unroll
      for (int ni = 0; ni < 4; ++ni) {
        int n = n0 + wn*64 + ni*16 + lrow;
        int bidx = n >> 12;
        int l = n & 4095;
        out[((size_t)bidx << 22) + ((size_t)vrow << 12) + l] = acc[mi][ni][r] + bv;
      }
    }
  }
}

// ---------------------------------------------------------------------------
// Workspace layout (bytes):
//   Kf   @ 0          : 1024 * 4104 * 8  = 33,619,968
//   Wbf  @ 33,619,968 : 1048576 * 2      =  2,097,152
//   ynat @ 35,717,120 : 33554432 * 2     = 67,108,864
//   yT   @ 102,825,984: 33554432 * 2     = 67,108,864   (total 169,934,848)
// ---------------------------------------------------------------------------
extern "C" void kernel_launch(void* const* d_in, const int* in_sizes, int n_in,
                              void* d_out, int out_size, void* d_ws, size_t ws_size,
                              hipStream_t stream)
{
  const float* u  = (const float*)d_in[0];
  const float* k0 = (const float*)d_in[1];
  const float* k1 = (const float*)d_in[2];
  const float* k2 = (const float*)d_in[3];
  const float* k3 = (const float*)d_in[4];
  const float* k4 = (const float*)d_in[5];
  const float* k5 = (const float*)d_in[6];
  const float* k6 = (const float*)d_in[7];
  const float* Dv = (const float*)d_in[8];
  const float* W  = (const float*)d_in[9];
  const float* bs = (const float*)d_in[10];
  float* out = (float*)d_out;

  char* ws = (char*)d_ws;
  float2* Kf  = (float2*)(ws);
  bf16*  Wbf  = (bf16*)(ws + 33619968);
  bf16*  ynat = (bf16*)(ws + 35717120);
  bf16*  yT   = (bf16*)(ws + 102825984);

  hipLaunchKernelGGL(prep_kf_kernel, dim3(1024), dim3(256), 65536, stream,
                     k0, k1, k2, k3, k4, k5, k6, Kf);
  hipLaunchKernelGGL(wcast_kernel, dim3(1024), dim3(256), 0, stream, W, Wbf);
  hipLaunchKernelGGL(fftconv_kernel, dim3(8192), dim3(256), 65536, stream, u, Dv, Kf, ynat);
  hipLaunchKernelGGL(transpose_kernel, dim3(64, 16, 8), dim3(256), 0, stream,
                     (const ushort*)ynat, (ushort*)yT);
  hipLaunchKernelGGL(gemm_kernel, dim3(8, 256), dim3(256), 0, stream, Wbf, yT, bs, out);
}

// Round 2
// 495.765 us; speedup vs baseline: 1.2746x; 1.2746x over previous
//
#include <hip/hip_runtime.h>
#include <cstdint>

// ---------------------------------------------------------------------------
// GConv: out = W @ gelu( ifft(fft(u)*fft(k_norm)) + u*D ) + bias
//   u: (8,1024,4096) f32; k0..k6: (1,1024,64) f32; D: (1,1024); W: (1024,1024); b: (1024,)
// Pipeline:
//   1. prep_kf   : build 4096-tap normalized kernel per d, rfft(8192) -> Kf (complex, /4096)
//   2. wcast     : W f32 -> bf16
//   3. fftconv   : per (b,d) row: rfft(u) * Kf -> irfft, + u*D, gelu -> y bf16 [b][d][l]
//                  (radix-16^3 register FFT, single 34.8KB LDS buffer, 4 blocks/CU)
//   4. transpose : y -> yT bf16 [(b,l)][d]   (K-contiguous for MFMA B operand)
//   5. gemm      : out[b][v][l] = sum_u Wbf[v][u] * yT[(b,l)][u] + bias[v]  (16x16x32 bf16 MFMA)
// ---------------------------------------------------------------------------

#define TWO_PI 6.283185307179586f

typedef __bf16 bf16;
typedef __bf16 bf16x4 __attribute__((ext_vector_type(4)));
typedef __bf16 bf16x8 __attribute__((ext_vector_type(8)));
typedef float  f32x4  __attribute__((ext_vector_type(4)));

__device__ __forceinline__ float2 cadd(float2 a, float2 b){ return make_float2(a.x+b.x, a.y+b.y); }
__device__ __forceinline__ float2 csub(float2 a, float2 b){ return make_float2(a.x-b.x, a.y-b.y); }
__device__ __forceinline__ float2 cmul(float2 a, float2 b){ return make_float2(a.x*b.x-a.y*b.y, a.x*b.y+a.y*b.x); }

// ---------------------------------------------------------------------------
// In-register 16-point DFT (SIGN=-1 fwd / +1 inv), natural-order in/out.
// Two radix-4 layers; inter-layer twiddles are compile-time ω16^k constants.
// ---------------------------------------------------------------------------
template<int SIGN>
__device__ __forceinline__ float2 rot90(float2 c) {   // SIGN*i * c
  return (SIGN < 0) ? make_float2(c.y, -c.x) : make_float2(-c.y, c.x);
}

template<int SIGN>
__device__ __forceinline__ void dft16(float2 v[16])
{
  const float C1 = 0.92387953251128675613f;  // cos(2pi/16)
  const float S1 = 0.38268343236508977173f;  // sin(2pi/16)
  const float SQ = 0.70710678118654752440f;
  const float sg = (SIGN < 0) ? -1.0f : 1.0f;
  // w16[k] = e^{SIGN*2*pi*i*k/16} for k in {0..9}
  const float2 w16[10] = {
    make_float2(1.f, 0.f),        make_float2(C1,  sg*S1),
    make_float2(SQ,  sg*SQ),      make_float2(S1,  sg*C1),
    make_float2(0.f, sg*1.f),     make_float2(-S1, sg*C1),
    make_float2(-SQ, sg*SQ),      make_float2(-C1, sg*S1),
    make_float2(-1.f, 0.f),       make_float2(-C1, -sg*S1)
  };
  float2 w[16];
  // inner: DFT4 over s1 (stride 4), result -> w[s0 + 4*f0]
  #pragma unroll
  for (int s0 = 0; s0 < 4; ++s0) {
    float2 a0 = v[s0], a1 = v[s0+4], a2 = v[s0+8], a3 = v[s0+12];
    float2 t0 = cadd(a0,a2), t1 = csub(a0,a2);
    float2 t2 = cadd(a1,a3);
    float2 j3 = rot90<SIGN>(csub(a1,a3));
    w[s0+0]  = cadd(t0,t2);
    w[s0+4]  = cadd(t1,j3);
    w[s0+8]  = csub(t0,t2);
    w[s0+12] = csub(t1,j3);
  }
  // twiddle: w[s0+4f0] *= w16[s0*f0]
  #pragma unroll
  for (int s0 = 1; s0 < 4; ++s0)
    #pragma unroll
    for (int f0 = 1; f0 < 4; ++f0)
      w[s0+4*f0] = cmul(w[s0+4*f0], w16[s0*f0]);
  // outer: DFT4 over s0 for each f0 -> v[f0 + 4*f1]
  #pragma unroll
  for (int f0 = 0; f0 < 4; ++f0) {
    float2 a0 = w[4*f0], a1 = w[1+4*f0], a2 = w[2+4*f0], a3 = w[3+4*f0];
    float2 t0 = cadd(a0,a2), t1 = csub(a0,a2);
    float2 t2 = cadd(a1,a3);
    float2 j3 = rot90<SIGN>(csub(a1,a3));
    v[f0+0]  = cadd(t0,t2);
    v[f0+4]  = cadd(t1,j3);
    v[f0+8]  = csub(t0,t2);
    v[f0+12] = csub(t1,j3);
  }
}

// twiddle v[f] *= w1^f, f=1..15, w1 from one sincos + recurrence
__device__ __forceinline__ void twiddle15(float2 v[16], float ang)
{
  float sn, cs; __sincosf(ang, &sn, &cs);
  float2 w1 = make_float2(cs, sn);
  float2 cur = w1;
  v[1] = cmul(v[1], cur);
  #pragma unroll
  for (int f = 2; f < 16; ++f) { cur = cmul(cur, w1); v[f] = cmul(v[f], cur); }
}

// padded natural-order LDS address: P(n) = n + n/16  (4096 -> 4352 slots)
#define LDSP(n) ((n) + ((n) >> 4))

// ---------------------------------------------------------------------------
// Legacy ping-pong radix-4 FFT (used only by prep_kf; runs once, 1024 blocks)
// ---------------------------------------------------------------------------
template<int SIGN>
__device__ inline void fft4096(float2* bufA, float2* bufB, int tid)
{
  float2* src = bufA;
  float2* dst = bufB;
  #pragma unroll
  for (int s = 0; s < 6; ++s) {
    const int m = 1 << (2*s);
    __syncthreads();
    #pragma unroll
    for (int it = 0; it < 4; ++it) {
      int bid = tid + it*256;
      int k = bid & (m-1);
      int j = bid >> (2*s);
      int rbase = k + m*j;
      float2 c0 = src[rbase];
      float2 c1 = src[rbase + 1024];
      float2 c2 = src[rbase + 2048];
      float2 c3 = src[rbase + 3072];
      float2 t0 = cadd(c0, c2);
      float2 t1 = csub(c0, c2);
      float2 t2 = cadd(c1, c3);
      float2 dd = csub(c1, c3);
      float2 t3 = (SIGN < 0) ? make_float2(dd.y, -dd.x) : make_float2(-dd.y, dd.x);
      float ang = (float)SIGN * (TWO_PI/4096.0f) * (float)(j << (2*s));
      float sn, cs;
      __sincosf(ang, &sn, &cs);
      float2 w1 = make_float2(cs, sn);
      float2 w2 = cmul(w1, w1);
      float2 w3 = cmul(w2, w1);
      int wbase = k + 4*m*j;
      dst[wbase]       = cadd(t0, t2);
      dst[wbase + m]   = cmul(w1, cadd(t1, t3));
      dst[wbase + 2*m] = cmul(w2, csub(t0, t2));
      dst[wbase + 3*m] = cmul(w3, csub(t1, t3));
    }
    float2* tmp = src; src = dst; dst = tmp;
  }
  __syncthreads();
}

// ---------------------------------------------------------------------------
// Kernel 1: build normalized conv kernel per channel d, rfft(8192) via packed
// complex FFT(4096), store Kf[d][j] = X_k[j]/4096 for j=0..4096 (row stride 4104).
// ---------------------------------------------------------------------------
__global__ __launch_bounds__(256) void prep_kf_kernel(
    const float* __restrict__ k0, const float* __restrict__ k1, const float* __restrict__ k2,
    const float* __restrict__ k3, const float* __restrict__ k4, const float* __restrict__ k5,
    const float* __restrict__ k6, float2* __restrict__ Kf)
{
  extern __shared__ __align__(16) float2 smem[];
  float2* bufA = smem;
  float2* bufB = smem + 4096;
  float*  kk   = (float*)bufB;
  float*  red  = (float*)bufA;
  int tid = threadIdx.x;
  int d = blockIdx.x;
  const float* kp[7] = { k0 + d*64, k1 + d*64, k2 + d*64, k3 + d*64,
                         k4 + d*64, k5 + d*64, k6 + d*64 };
  #pragma unroll
  for (int it = 0; it < 16; ++it) {
    int idx = tid + it*256;
    int seg, s, base;
    if      (idx <   64) { seg=0; s=1;  base=0;    }
    else if (idx <  128) { seg=1; s=1;  base=64;   }
    else if (idx <  256) { seg=2; s=2;  base=128;  }
    else if (idx <  512) { seg=3; s=4;  base=256;  }
    else if (idx < 1024) { seg=4; s=8;  base=512;  }
    else if (idx < 2048) { seg=5; s=16; base=1024; }
    else                 { seg=6; s=32; base=2048; }
    int j = idx - base;
    float coord = ((float)j + 0.5f) / (float)s - 0.5f;
    coord = fminf(fmaxf(coord, 0.0f), 63.0f);
    int lo = (int)coord;
    int hi = min(lo + 1, 63);
    float w = coord - (float)lo;
    const float* kpp = kp[seg];
    kk[idx] = kpp[lo] * (1.0f - w) + kpp[hi] * w;
  }
  __syncthreads();
  float psum = 0.f;
  #pragma unroll
  for (int it = 0; it < 16; ++it) { float v = kk[tid + it*256]; psum += v*v; }
  red[tid] = psum;
  __syncthreads();
  if (tid == 0) {
    float tot = 0.f;
    for (int i = 0; i < 256; ++i) tot += red[i];
    red[0] = 1.0f / sqrtf(tot);
  }
  __syncthreads();
  float inv = red[0];
  __syncthreads();
  #pragma unroll
  for (int it = 0; it < 8; ++it) {
    int m_ = tid + it*256;
    bufA[m_]        = make_float2(kk[2*m_] * inv, kk[2*m_+1] * inv);
    bufA[m_ + 2048] = make_float2(0.f, 0.f);
  }
  fft4096<-1>(bufA, bufB, tid);
  const float S = 1.0f/4096.0f;
  float2* kfr = Kf + (size_t)d * 4104;
  for (int j = tid; j < 2048; j += 256) {
    if (j == 0) {
      float2 Z0 = bufA[0];
      kfr[0]    = make_float2((Z0.x + Z0.y) * S, 0.f);
      kfr[4096] = make_float2((Z0.x - Z0.y) * S, 0.f);
      float2 Zh = bufA[2048];
      kfr[2048] = make_float2(Zh.x * S, -Zh.y * S);
    } else {
      float2 Zj = bufA[j];
      float2 Zm = bufA[4096 - j];
      float2 E = make_float2(0.5f*(Zj.x + Zm.x), 0.5f*(Zj.y - Zm.y));
      float2 O = make_float2(0.5f*(Zj.y + Zm.y), 0.5f*(Zm.x - Zj.x));
      float ang = -(TWO_PI/8192.0f) * (float)j;
      float sn, cs; __sincosf(ang, &sn, &cs);
      float2 W = make_float2(cs, sn);
      float2 T = cmul(W, O);
      kfr[j]        = make_float2((E.x + T.x)*S, (E.y + T.y)*S);
      kfr[4096 - j] = make_float2((E.x - T.x)*S, (T.y - E.y)*S);
    }
  }
}

// ---------------------------------------------------------------------------
// Kernel 2: W f32 -> bf16
// ---------------------------------------------------------------------------
__global__ __launch_bounds__(256) void wcast_kernel(const float* __restrict__ W,
                                                    bf16* __restrict__ Wbf)
{
  int i4 = blockIdx.x * 256 + threadIdx.x;
  float4 v = ((const float4*)W)[i4];
  bf16x4 h; h[0] = (bf16)v.x; h[1] = (bf16)v.y; h[2] = (bf16)v.z; h[3] = (bf16)v.w;
  *(bf16x4*)(Wbf + (size_t)i4 * 4) = h;
}

// ---------------------------------------------------------------------------
// Kernel 3: per-(b,d) row FFT convolution, radix-16^3 register FFT.
// 256 threads x 16 float2 regs; single padded LDS buffer (34,816 B).
// Digits: X[f1 + 16*f2 + 256*k3]; level assignments:
//   L1: thread t (s-elements, stride 256); L2: (f1=t>>4, t0=t&15); L3: (f1, f2=t&15)
// LDS geometry: block f1 stride 272; inside: [t0*17 + x] / [t + (t>>4)] as noted.
// ---------------------------------------------------------------------------
__global__ __launch_bounds__(256, 4) void fftconv_kernel(
    const float* __restrict__ u, const float* __restrict__ Dv,
    const float2* __restrict__ Kf, bf16* __restrict__ ynat)
{
  __shared__ __align__(16) float2 lds[4352];
  int tid = threadIdx.x;
  int d = blockIdx.x >> 3;
  int b = blockIdx.x & 7;
  int row = b * 1024 + d;
  const float* uRow = u + (size_t)row * 4096;
  const float2* uR2 = (const float2*)uRow;
  const float4* uR4 = (const float4*)uRow;

  float2 v[16];
  int f1g = tid >> 4;        // level-2/3 block digit
  int lo4 = tid & 15;        // level-2: t0; level-3: f2

  // ======== forward FFT (SIGN=-1) ========
  // L1: load z[t+256s] = (u[2m], u[2m+1]) directly from global; zero-pad s>=8
  #pragma unroll
  for (int s = 0; s < 8; ++s)  v[s] = uR2[tid + 256*s];
  #pragma unroll
  for (int s = 8; s < 16; ++s) v[s] = make_float2(0.f, 0.f);
  dft16<-1>(v);
  twiddle15(v, -(TWO_PI/4096.0f) * (float)tid);
  {
    int base = tid + (tid >> 4);
    #pragma unroll
    for (int f = 0; f < 16; ++f) lds[f*272 + base] = v[f];
  }
  __syncthreads();
  // L2: read W1[f1; t0+16*t1]
  #pragma unroll
  for (int t1 = 0; t1 < 16; ++t1) v[t1] = lds[f1g*272 + lo4 + 17*t1];
  __syncthreads();
  dft16<-1>(v);
  twiddle15(v, -(TWO_PI/256.0f) * (float)lo4);
  #pragma unroll
  for (int f = 0; f < 16; ++f) lds[f1g*272 + lo4*17 + f] = v[f];
  __syncthreads();
  // L3: read W2[f1; f2; t0]
  #pragma unroll
  for (int t0 = 0; t0 < 16; ++t0) v[t0] = lds[f1g*272 + t0*17 + lo4];
  __syncthreads();
  dft16<-1>(v);
  #pragma unroll
  for (int k3 = 0; k3 < 16; ++k3) lds[f1g + 17*lo4 + 272*k3] = v[k3];  // natural P(n)
  __syncthreads();

  // ======== pointwise: unpack rfft, multiply Kf, repack for inverse ========
  const float2* kfr = Kf + (size_t)d * 4104;
  #pragma unroll
  for (int it = 0; it < 8; ++it) {
    int j = tid + it*256;
    if (j == 0) {
      float2 Z0 = lds[LDSP(0)];
      float X0 = Z0.x + Z0.y;
      float XM = Z0.x - Z0.y;
      float P0 = X0 * kfr[0].x;
      float PM = XM * kfr[4096].x;
      lds[LDSP(0)] = make_float2(0.5f*(P0 + PM), 0.5f*(P0 - PM));
      float2 Zh = lds[LDSP(2048)];
      float2 Xh = make_float2(Zh.x, -Zh.y);
      float2 Ph = cmul(Xh, kfr[2048]);
      lds[LDSP(2048)] = make_float2(Ph.x, -Ph.y);
    } else {
      float2 Zj = lds[LDSP(j)];
      float2 Zm = lds[LDSP(4096 - j)];
      float2 E = make_float2(0.5f*(Zj.x + Zm.x), 0.5f*(Zj.y - Zm.y));
      float2 O = make_float2(0.5f*(Zj.y + Zm.y), 0.5f*(Zm.x - Zj.x));
      float ang = -(TWO_PI/8192.0f) * (float)j;
      float sn, cs; __sincosf(ang, &sn, &cs);
      float2 W = make_float2(cs, sn);
      float2 T = cmul(W, O);
      float2 Xj = cadd(E, T);
      float2 Xm = make_float2(E.x - T.x, T.y - E.y);
      float2 Pj = cmul(Xj, kfr[j]);
      float2 Pm = cmul(Xm, kfr[4096 - j]);
      float2 Ep = make_float2(0.5f*(Pj.x + Pm.x), 0.5f*(Pj.y - Pm.y));
      float2 V  = make_float2(0.5f*(Pj.x - Pm.x), 0.5f*(Pj.y + Pm.y));
      float2 Wi = make_float2(cs, -sn);
      float2 Op = cmul(Wi, V);
      lds[LDSP(j)]        = make_float2(Ep.x - Op.y, Ep.y + Op.x);
      lds[LDSP(4096 - j)] = make_float2(Ep.x + Op.y, Op.x - Ep.y);
    }
  }
  __syncthreads();

  // ======== inverse FFT (SIGN=+1), 1/4096 folded into Kf ========
  // L1: read Q[t+256s] from natural P()
  {
    int base = tid + (tid >> 4);
    #pragma unroll
    for (int s = 0; s < 16; ++s) v[s] = lds[base + 272*s];
    __syncthreads();
    dft16<1>(v);
    twiddle15(v, (TWO_PI/4096.0f) * (float)tid);
    #pragma unroll
    for (int f = 0; f < 16; ++f) lds[f*272 + base] = v[f];
  }
  __syncthreads();
  // L2
  #pragma unroll
  for (int t1 = 0; t1 < 16; ++t1) v[t1] = lds[f1g*272 + lo4 + 17*t1];
  __syncthreads();
  dft16<1>(v);
  twiddle15(v, (TWO_PI/256.0f) * (float)lo4);
  #pragma unroll
  for (int f = 0; f < 16; ++f) lds[f1g*272 + lo4*17 + f] = v[f];
  __syncthreads();
  // L3
  #pragma unroll
  for (int t0 = 0; t0 < 16; ++t0) v[t0] = lds[f1g*272 + t0*17 + lo4];
  __syncthreads();
  dft16<1>(v);
  #pragma unroll
  for (int k3 = 0; k3 < 16; ++k3) lds[f1g + 17*lo4 + 272*k3] = v[k3];  // natural P(n)
  __syncthreads();

  // ======== epilogue: +u*D, exact gelu, bf16 store ========
  // thread t handles packed m = 8t..8t+7 (samples 16t..16t+15); P(8t+i)=P(8t)+i
  float Dd = Dv[d];
  float vals[16];
  int base = 8*tid + (tid >> 1);
  #pragma unroll
  for (int i = 0; i < 8; ++i) {
    float2 q = lds[base + i];
    vals[2*i]   = q.x;
    vals[2*i+1] = q.y;
  }
  #pragma unroll
  for (int c = 0; c < 4; ++c) {
    float4 uu = uR4[tid*4 + c];
    vals[4*c+0] += uu.x * Dd;
    vals[4*c+1] += uu.y * Dd;
    vals[4*c+2] += uu.z * Dd;
    vals[4*c+3] += uu.w * Dd;
  }
  union { bf16 h[16]; uint4 q[2]; } st;
  #pragma unroll
  for (int i = 0; i < 16; ++i) {
    float x = vals[i];
    float g = 0.5f * x * (1.0f + erff(x * 0.70710678118654752440f));
    st.h[i] = (bf16)g;
  }
  uint4* outp = (uint4*)(ynat + (size_t)row * 4096 + tid * 16);
  outp[0] = st.q[0];
  outp[1] = st.q[1];
}

// ---------------------------------------------------------------------------
// Kernel 4: y [b][u][l] bf16 -> yT [(b,l)][u] bf16 (64x64 tiles via LDS)
// ---------------------------------------------------------------------------
__global__ __launch_bounds__(256) void transpose_kernel(const ushort* __restrict__ ynat,
                                                        ushort* __restrict__ yT)
{
  __shared__ ushort T[64 * 68];
  int tid = threadIdx.x;
  int l0 = blockIdx.x * 64;
  int u0 = blockIdx.y * 64;
  int b  = blockIdx.z;
  const ushort* src = ynat + ((size_t)(b*1024 + u0)) * 4096 + l0;
  #pragma unroll
  for (int it = 0; it < 4; ++it) {
    int c = tid + it*256;
    int r = c >> 4;
    int c4 = c & 15;
    ushort4 v = *(const ushort4*)(src + (size_t)r * 4096 + c4*4);
    *(ushort4*)&T[r*68 + c4*4] = v;
  }
  __syncthreads();
  ushort* dst = yT + ((size_t)(b*4096 + l0)) * 1024 + u0;
  #pragma unroll
  for (int it = 0; it < 4; ++it) {
    int c = tid + it*256;
    int lr = c >> 4;
    int u4 = c & 15;
    ushort4 v;
    v.x = T[(u4*4+0)*68 + lr];
    v.y = T[(u4*4+1)*68 + lr];
    v.z = T[(u4*4+2)*68 + lr];
    v.w = T[(u4*4+3)*68 + lr];
    *(ushort4*)(dst + (size_t)lr * 1024 + u4*4) = v;
  }
}

// ---------------------------------------------------------------------------
// Kernel 5: GEMM out[b][v][l] = sum_u Wbf[v][u] * yT[(b,l)][u] + bias[v]
// M=1024(v), N=32768(b,l), K=1024(u); 128x128 tile, BK=32, 16x16x32 bf16 MFMA
// ---------------------------------------------------------------------------
#define GL_LDS16(g, l) __builtin_amdgcn_global_load_lds( \
    (const __attribute__((address_space(1))) void*)(g),  \
    (__attribute__((address_space(3))) void*)(l), 16, 0, 0)

__global__ __launch_bounds__(256) void gemm_kernel(
    const bf16* __restrict__ A,      // Wbf [v][u] 1024x1024
    const bf16* __restrict__ B,      // yT [(b,l)][u] 32768x1024
    const float* __restrict__ bias,
    float* __restrict__ out)
{
  __shared__ bf16 ldsA[128 * 32];
  __shared__ bf16 ldsB[128 * 32];
  int tid = threadIdx.x;
  int lane = tid & 63;
  int w = tid >> 6;
  int wm = w & 1, wn = w >> 1;
  int m0 = blockIdx.x * 128;
  int n0 = blockIdx.y * 128;
  int lrow = lane & 15;
  int quad = lane >> 4;
  f32x4 acc[4][4] = {};
  for (int kk0 = 0; kk0 < 1024; kk0 += 32) {
    __syncthreads();
    #pragma unroll
    for (int i = 0; i < 2; ++i) {
      int c = tid + 256*i;
      int row = c >> 2;
      int kc = c & 3;
      const bf16* ga = A + (size_t)(m0 + row) * 1024 + kk0 + kc*8;
      bf16* la = ldsA + (size_t)(w*64 + 256*i) * 8;
      GL_LDS16(ga, la);
      const bf16* gb = B + (size_t)(n0 + row) * 1024 + kk0 + kc*8;
      bf16* lb = ldsB + (size_t)(w*64 + 256*i) * 8;
      GL_LDS16(gb, lb);
    }
    __syncthreads();
    bf16x8 a[4], bq[4];
    #pragma unroll
    for (int mi = 0; mi < 4; ++mi)
      a[mi] = *(const bf16x8*)&ldsA[(wm*64 + mi*16 + lrow)*32 + quad*8];
    #pragma unroll
    for (int ni = 0; ni < 4; ++ni)
      bq[ni] = *(const bf16x8*)&ldsB[(wn*64 + ni*16 + lrow)*32 + quad*8];
    #pragma unroll
    for (int mi = 0; mi < 4; ++mi)
      #pragma unroll
      for (int ni = 0; ni < 4; ++ni)
        acc[mi][ni] = __builtin_amdgcn_mfma_f32_16x16x32_bf16(a[mi], bq[ni], acc[mi][ni], 0, 0, 0);
  }
  #pragma unroll
  for (int mi = 0; mi < 4; ++mi) {
    #pragma unroll
    for (int r = 0; r < 4; ++r) {
      int vrow = m0 + wm*64 + mi*16 + quad*4 + r;
      float bv = bias[vrow];
      #pragma unroll
      for (int ni = 0; ni < 4; ++ni) {
        int n = n0 + wn*64 + ni*16 + lrow;
        int bidx = n >> 12;
        int l = n & 4095;
        out[((size_t)bidx << 22) + ((size_t)vrow << 12) + l] = acc[mi][ni][r] + bv;
      }
    }
  }
}

// ---------------------------------------------------------------------------
// Workspace layout (bytes):
//   Kf   @ 0          : 1024 * 4104 * 8  = 33,619,968
//   Wbf  @ 33,619,968 : 1048576 * 2      =  2,097,152
//   ynat @ 35,717,120 : 33554432 * 2     = 67,108,864
//   yT   @ 102,825,984: 33554432 * 2     = 67,108,864   (total 169,934,848)
// ---------------------------------------------------------------------------
extern "C" void kernel_launch(void* const* d_in, const int* in_sizes, int n_in,
                              void* d_out, int out_size, void* d_ws, size_t ws_size,
                              hipStream_t stream)
{
  const float* u  = (const float*)d_in[0];
  const float* k0 = (const float*)d_in[1];
  const float* k1 = (const float*)d_in[2];
  const float* k2 = (const float*)d_in[3];
  const float* k3 = (const float*)d_in[4];
  const float* k4 = (const float*)d_in[5];
  const float* k5 = (const float*)d_in[6];
  const float* k6 = (const float*)d_in[7];
  const float* Dv = (const float*)d_in[8];
  const float* W  = (const float*)d_in[9];
  const float* bs = (const float*)d_in[10];
  float* out = (float*)d_out;

  char* ws = (char*)d_ws;
  float2* Kf  = (float2*)(ws);
  bf16*  Wbf  = (bf16*)(ws + 33619968);
  bf16*  ynat = (bf16*)(ws + 35717120);
  bf16*  yT   = (bf16*)(ws + 102825984);

  hipLaunchKernelGGL(prep_kf_kernel, dim3(1024), dim3(256), 65536, stream,
                     k0, k1, k2, k3, k4, k5, k6, Kf);
  hipLaunchKernelGGL(wcast_kernel, dim3(1024), dim3(256), 0, stream, W, Wbf);
  hipLaunchKernelGGL(fftconv_kernel, dim3(8192), dim3(256), 0, stream, u, Dv, Kf, ynat);
  hipLaunchKernelGGL(transpose_kernel, dim3(64, 16, 8), dim3(256), 0, stream,
                     (const ushort*)ynat, (ushort*)yT);
  hipLaunchKernelGGL(gemm_kernel, dim3(8, 256), dim3(256), 0, stream, Wbf, yT, bs, out);
}

// Round 3
// 470.340 us; speedup vs baseline: 1.3435x; 1.0541x over previous
//
#include <hip/hip_runtime.h>
#include <cstdint>

// ---------------------------------------------------------------------------
// GConv: out = W @ gelu( ifft(fft(u)*fft(k_norm)) + u*D ) + bias
//   u: (8,1024,4096) f32; k0..k6: (1,1024,64) f32; D: (1,1024); W: (1024,1024); b: (1024,)
// Pipeline:
//   1. prep_kf   : build 4096-tap normalized kernel per d, rfft(8192), then fold the
//                  whole unpack->xK->repack pointwise operator into 3 complex coeffs
//                  per (d,j):  Qj = a*Zj + b*conj(Zm),  Qm = -conj(b)*conj(Zj) + dl*Zm
//   2. wcast     : W f32 -> bf16
//   3. fftconv   : per (b,d) row: fwd FFT -> fused pointwise -> inv FFT, + u*D,
//                  tanh-GELU -> y bf16 [b][d][l]  (radix-16^3 register FFT)
//   4. transpose : y -> yT bf16 [(b,l)][d]   (K-contiguous for MFMA B operand)
//   5. gemm      : out[b][v][l] = sum_u Wbf[v][u] * yT[(b,l)][u] + bias[v]  (16x16x32 bf16 MFMA)
// WS alias: CF tables (50.3MB, phase A) share bytes with yT (67MB, phase B).
// ---------------------------------------------------------------------------

#define TWO_PI 6.283185307179586f

typedef __bf16 bf16;
typedef __bf16 bf16x4 __attribute__((ext_vector_type(4)));
typedef __bf16 bf16x8 __attribute__((ext_vector_type(8)));
typedef float  f32x4  __attribute__((ext_vector_type(4)));

__device__ __forceinline__ float2 cadd(float2 a, float2 b){ return make_float2(a.x+b.x, a.y+b.y); }
__device__ __forceinline__ float2 csub(float2 a, float2 b){ return make_float2(a.x-b.x, a.y-b.y); }
__device__ __forceinline__ float2 cmul(float2 a, float2 b){ return make_float2(a.x*b.x-a.y*b.y, a.x*b.y+a.y*b.x); }

// ---------------------------------------------------------------------------
// In-register 16-point DFT (SIGN=-1 fwd / +1 inv), natural-order in/out.
// ---------------------------------------------------------------------------
template<int SIGN>
__device__ __forceinline__ float2 rot90(float2 c) {   // SIGN*i * c
  return (SIGN < 0) ? make_float2(c.y, -c.x) : make_float2(-c.y, c.x);
}

template<int SIGN>
__device__ __forceinline__ void dft16(float2 v[16])
{
  const float C1 = 0.92387953251128675613f;
  const float S1 = 0.38268343236508977173f;
  const float SQ = 0.70710678118654752440f;
  const float sg = (SIGN < 0) ? -1.0f : 1.0f;
  const float2 w16[10] = {
    make_float2(1.f, 0.f),        make_float2(C1,  sg*S1),
    make_float2(SQ,  sg*SQ),      make_float2(S1,  sg*C1),
    make_float2(0.f, sg*1.f),     make_float2(-S1, sg*C1),
    make_float2(-SQ, sg*SQ),      make_float2(-C1, sg*S1),
    make_float2(-1.f, 0.f),       make_float2(-C1, -sg*S1)
  };
  float2 w[16];
  #pragma unroll
  for (int s0 = 0; s0 < 4; ++s0) {
    float2 a0 = v[s0], a1 = v[s0+4], a2 = v[s0+8], a3 = v[s0+12];
    float2 t0 = cadd(a0,a2), t1 = csub(a0,a2);
    float2 t2 = cadd(a1,a3);
    float2 j3 = rot90<SIGN>(csub(a1,a3));
    w[s0+0]  = cadd(t0,t2);
    w[s0+4]  = cadd(t1,j3);
    w[s0+8]  = csub(t0,t2);
    w[s0+12] = csub(t1,j3);
  }
  #pragma unroll
  for (int s0 = 1; s0 < 4; ++s0)
    #pragma unroll
    for (int f0 = 1; f0 < 4; ++f0)
      w[s0+4*f0] = cmul(w[s0+4*f0], w16[s0*f0]);
  #pragma unroll
  for (int f0 = 0; f0 < 4; ++f0) {
    float2 a0 = w[4*f0], a1 = w[1+4*f0], a2 = w[2+4*f0], a3 = w[3+4*f0];
    float2 t0 = cadd(a0,a2), t1 = csub(a0,a2);
    float2 t2 = cadd(a1,a3);
    float2 j3 = rot90<SIGN>(csub(a1,a3));
    v[f0+0]  = cadd(t0,t2);
    v[f0+4]  = cadd(t1,j3);
    v[f0+8]  = csub(t0,t2);
    v[f0+12] = csub(t1,j3);
  }
}

__device__ __forceinline__ void twiddle15(float2 v[16], float ang)
{
  float sn, cs; __sincosf(ang, &sn, &cs);
  float2 w1 = make_float2(cs, sn);
  float2 cur = w1;
  v[1] = cmul(v[1], cur);
  #pragma unroll
  for (int f = 2; f < 16; ++f) { cur = cmul(cur, w1); v[f] = cmul(v[f], cur); }
}

#define LDSP(n) ((n) + ((n) >> 4))

// ---------------------------------------------------------------------------
// Legacy ping-pong radix-4 FFT (used only by prep_kf)
// ---------------------------------------------------------------------------
template<int SIGN>
__device__ inline void fft4096(float2* bufA, float2* bufB, int tid)
{
  float2* src = bufA;
  float2* dst = bufB;
  #pragma unroll
  for (int s = 0; s < 6; ++s) {
    const int m = 1 << (2*s);
    __syncthreads();
    #pragma unroll
    for (int it = 0; it < 4; ++it) {
      int bid = tid + it*256;
      int k = bid & (m-1);
      int j = bid >> (2*s);
      int rbase = k + m*j;
      float2 c0 = src[rbase];
      float2 c1 = src[rbase + 1024];
      float2 c2 = src[rbase + 2048];
      float2 c3 = src[rbase + 3072];
      float2 t0 = cadd(c0, c2);
      float2 t1 = csub(c0, c2);
      float2 t2 = cadd(c1, c3);
      float2 dd = csub(c1, c3);
      float2 t3 = (SIGN < 0) ? make_float2(dd.y, -dd.x) : make_float2(-dd.y, dd.x);
      float ang = (float)SIGN * (TWO_PI/4096.0f) * (float)(j << (2*s));
      float sn, cs;
      __sincosf(ang, &sn, &cs);
      float2 w1 = make_float2(cs, sn);
      float2 w2 = cmul(w1, w1);
      float2 w3 = cmul(w2, w1);
      int wbase = k + 4*m*j;
      dst[wbase]       = cadd(t0, t2);
      dst[wbase + m]   = cmul(w1, cadd(t1, t3));
      dst[wbase + 2*m] = cmul(w2, csub(t0, t2));
      dst[wbase + 3*m] = cmul(w3, csub(t1, t3));
    }
    float2* tmp = src; src = dst; dst = tmp;
  }
  __syncthreads();
}

// ---------------------------------------------------------------------------
// Kernel 1: normalized kernel FFT -> fused pointwise coefficient tables.
//   CFa[d][j], CFb[d][j], CFd[d][j] for j=1..2047; slot 0 packs the j=0 (DC /
//   Nyquist-of-packed) pair in CFa[0] and conj(K2048) in CFb[0].
// ---------------------------------------------------------------------------
__global__ __launch_bounds__(256) void prep_kf_kernel(
    const float* __restrict__ k0, const float* __restrict__ k1, const float* __restrict__ k2,
    const float* __restrict__ k3, const float* __restrict__ k4, const float* __restrict__ k5,
    const float* __restrict__ k6,
    float2* __restrict__ CFa, float2* __restrict__ CFb, float2* __restrict__ CFd)
{
  extern __shared__ __align__(16) float2 smem[];
  float2* bufA = smem;
  float2* bufB = smem + 4096;
  float*  kk   = (float*)bufB;
  float*  red  = (float*)bufA;
  int tid = threadIdx.x;
  int d = blockIdx.x;
  const float* kp[7] = { k0 + d*64, k1 + d*64, k2 + d*64, k3 + d*64,
                         k4 + d*64, k5 + d*64, k6 + d*64 };
  #pragma unroll
  for (int it = 0; it < 16; ++it) {
    int idx = tid + it*256;
    int seg, s, base;
    if      (idx <   64) { seg=0; s=1;  base=0;    }
    else if (idx <  128) { seg=1; s=1;  base=64;   }
    else if (idx <  256) { seg=2; s=2;  base=128;  }
    else if (idx <  512) { seg=3; s=4;  base=256;  }
    else if (idx < 1024) { seg=4; s=8;  base=512;  }
    else if (idx < 2048) { seg=5; s=16; base=1024; }
    else                 { seg=6; s=32; base=2048; }
    int j = idx - base;
    float coord = ((float)j + 0.5f) / (float)s - 0.5f;
    coord = fminf(fmaxf(coord, 0.0f), 63.0f);
    int lo = (int)coord;
    int hi = min(lo + 1, 63);
    float w = coord - (float)lo;
    const float* kpp = kp[seg];
    kk[idx] = kpp[lo] * (1.0f - w) + kpp[hi] * w;
  }
  __syncthreads();
  float psum = 0.f;
  #pragma unroll
  for (int it = 0; it < 16; ++it) { float v = kk[tid + it*256]; psum += v*v; }
  red[tid] = psum;
  __syncthreads();
  if (tid < 64) {
    float s = red[tid] + red[tid+64] + red[tid+128] + red[tid+192];
    #pragma unroll
    for (int off = 32; off >= 1; off >>= 1) s += __shfl_xor(s, off, 64);
    if (tid == 0) red[0] = 1.0f / sqrtf(s);
  }
  __syncthreads();
  float inv = red[0];
  __syncthreads();
  #pragma unroll
  for (int it = 0; it < 8; ++it) {
    int m_ = tid + it*256;
    bufA[m_]        = make_float2(kk[2*m_] * inv, kk[2*m_+1] * inv);
    bufA[m_ + 2048] = make_float2(0.f, 0.f);
  }
  fft4096<-1>(bufA, bufB, tid);
  const float S = 1.0f/4096.0f;   // inverse-FFT normalization folded into K
  float2* cfa = CFa + (size_t)d * 2048;
  float2* cfb = CFb + (size_t)d * 2048;
  float2* cfd = CFd + (size_t)d * 2048;
  for (int j = tid; j < 2048; j += 256) {
    if (j == 0) {
      float2 Z0 = bufA[0];
      float K0 = (Z0.x + Z0.y) * S;      // real K at packed bin 0
      float KM = (Z0.x - Z0.y) * S;      // real K at packed bin 4096
      cfa[0] = make_float2(0.5f*(K0 + KM), 0.5f*(K0 - KM));
      float2 Zh = bufA[2048];
      cfb[0] = make_float2(Zh.x * S, Zh.y * S);   // conj(K2048)
      cfd[0] = make_float2(0.f, 0.f);
    } else {
      float2 Zj = bufA[j];
      float2 Zm = bufA[4096 - j];
      float2 E = make_float2(0.5f*(Zj.x + Zm.x), 0.5f*(Zj.y - Zm.y));
      float2 O = make_float2(0.5f*(Zj.y + Zm.y), 0.5f*(Zm.x - Zj.x));
      float ang = -(TWO_PI/8192.0f) * (float)j;   // W = e^{-i theta}
      float sn, cs; __sincosf(ang, &sn, &cs);
      float2 W = make_float2(cs, sn);
      float2 T = cmul(W, O);
      float2 Kj  = make_float2((E.x + T.x)*S, (E.y + T.y)*S);   // K_j
      float2 Kmc = make_float2((E.x - T.x)*S, (E.y - T.y)*S);   // conj(K_{4096-j})
      float s = -sn;   // sin(theta)
      float c = cs;    // cos(theta)
      // alpha = 0.5[(1-s)Kj + (1+s)Kmc]
      float2 al = make_float2(0.5f*((1.f-s)*Kj.x + (1.f+s)*Kmc.x),
                              0.5f*((1.f-s)*Kj.y + (1.f+s)*Kmc.y));
      // beta = (i c/2)(Kj - Kmc)
      float2 z = make_float2(Kj.x - Kmc.x, Kj.y - Kmc.y);
      float2 be = make_float2(-0.5f*c*z.y, 0.5f*c*z.x);
      // delta = conj(0.5[(1+s)Kj + (1-s)Kmc])
      float2 de = make_float2( 0.5f*((1.f+s)*Kj.x + (1.f-s)*Kmc.x),
                              -0.5f*((1.f+s)*Kj.y + (1.f-s)*Kmc.y));
      cfa[j] = al; cfb[j] = be; cfd[j] = de;
    }
  }
}

// ---------------------------------------------------------------------------
// Kernel 2: W f32 -> bf16
// ---------------------------------------------------------------------------
__global__ __launch_bounds__(256) void wcast_kernel(const float* __restrict__ W,
                                                    bf16* __restrict__ Wbf)
{
  int i4 = blockIdx.x * 256 + threadIdx.x;
  float4 v = ((const float4*)W)[i4];
  bf16x4 h; h[0] = (bf16)v.x; h[1] = (bf16)v.y; h[2] = (bf16)v.z; h[3] = (bf16)v.w;
  *(bf16x4*)(Wbf + (size_t)i4 * 4) = h;
}

// ---------------------------------------------------------------------------
// Kernel 3: per-(b,d) row FFT convolution, radix-16^3 register FFT,
// fused pointwise (precomputed coeffs), tanh-GELU epilogue.
// ---------------------------------------------------------------------------
__global__ __launch_bounds__(256, 4) void fftconv_kernel(
    const float* __restrict__ u, const float* __restrict__ Dv,
    const float2* __restrict__ CFa, const float2* __restrict__ CFb,
    const float2* __restrict__ CFd, bf16* __restrict__ ynat)
{
  __shared__ __align__(16) float2 lds[4352];
  int tid = threadIdx.x;
  int d = blockIdx.x >> 3;
  int b = blockIdx.x & 7;
  int row = b * 1024 + d;
  const float* uRow = u + (size_t)row * 4096;
  const float2* uR2 = (const float2*)uRow;
  const float4* uR4 = (const float4*)uRow;

  float2 v[16];
  int f1g = tid >> 4;
  int lo4 = tid & 15;

  // ======== forward FFT ========
  #pragma unroll
  for (int s = 0; s < 8; ++s)  v[s] = uR2[tid + 256*s];
  #pragma unroll
  for (int s = 8; s < 16; ++s) v[s] = make_float2(0.f, 0.f);
  dft16<-1>(v);
  twiddle15(v, -(TWO_PI/4096.0f) * (float)tid);
  {
    int base = tid + (tid >> 4);
    #pragma unroll
    for (int f = 0; f < 16; ++f) lds[f*272 + base] = v[f];
  }
  __syncthreads();
  #pragma unroll
  for (int t1 = 0; t1 < 16; ++t1) v[t1] = lds[f1g*272 + lo4 + 17*t1];
  __syncthreads();
  dft16<-1>(v);
  twiddle15(v, -(TWO_PI/256.0f) * (float)lo4);
  #pragma unroll
  for (int f = 0; f < 16; ++f) lds[f1g*272 + lo4*17 + f] = v[f];
  __syncthreads();
  #pragma unroll
  for (int t0 = 0; t0 < 16; ++t0) v[t0] = lds[f1g*272 + t0*17 + lo4];
  __syncthreads();
  dft16<-1>(v);
  #pragma unroll
  for (int k3 = 0; k3 < 16; ++k3) lds[f1g + 17*lo4 + 272*k3] = v[k3];
  __syncthreads();

  // ======== fused pointwise: Qj = a*Zj + b*conj(Zm); Qm = -conj(b)*conj(Zj) + d*Zm
  const float2* cfa = CFa + (size_t)d * 2048;
  const float2* cfb = CFb + (size_t)d * 2048;
  const float2* cfd = CFd + (size_t)d * 2048;
  #pragma unroll
  for (int it = 0; it < 8; ++it) {
    int j = tid + it*256;
    if (j == 0) {
      float2 a0 = cfa[0];
      float2 Z0 = lds[LDSP(0)];
      lds[LDSP(0)] = make_float2(a0.x*Z0.x + a0.y*Z0.y, a0.y*Z0.x + a0.x*Z0.y);
      float2 b0 = cfb[0];
      float2 Zh = lds[LDSP(2048)];
      lds[LDSP(2048)] = cmul(Zh, b0);
    } else {
      float2 al = cfa[j];
      float2 be = cfb[j];
      float2 de = cfd[j];
      float2 Zj = lds[LDSP(j)];
      float2 Zm = lds[LDSP(4096 - j)];
      float2 Zmc = make_float2(Zm.x, -Zm.y);
      float2 Qj = cadd(cmul(al, Zj), cmul(be, Zmc));
      float2 nbc = make_float2(-be.x, be.y);
      float2 Zjc = make_float2(Zj.x, -Zj.y);
      float2 Qm = cadd(cmul(nbc, Zjc), cmul(de, Zm));
      lds[LDSP(j)]        = Qj;
      lds[LDSP(4096 - j)] = Qm;
    }
  }
  __syncthreads();

  // ======== inverse FFT ========
  {
    int base = tid + (tid >> 4);
    #pragma unroll
    for (int s = 0; s < 16; ++s) v[s] = lds[base + 272*s];
    __syncthreads();
    dft16<1>(v);
    twiddle15(v, (TWO_PI/4096.0f) * (float)tid);
    #pragma unroll
    for (int f = 0; f < 16; ++f) lds[f*272 + base] = v[f];
  }
  __syncthreads();
  #pragma unroll
  for (int t1 = 0; t1 < 16; ++t1) v[t1] = lds[f1g*272 + lo4 + 17*t1];
  __syncthreads();
  dft16<1>(v);
  twiddle15(v, (TWO_PI/256.0f) * (float)lo4);
  #pragma unroll
  for (int f = 0; f < 16; ++f) lds[f1g*272 + lo4*17 + f] = v[f];
  __syncthreads();
  #pragma unroll
  for (int t0 = 0; t0 < 16; ++t0) v[t0] = lds[f1g*272 + t0*17 + lo4];
  __syncthreads();
  dft16<1>(v);
  #pragma unroll
  for (int k3 = 0; k3 < 16; ++k3) lds[f1g + 17*lo4 + 272*k3] = v[k3];
  __syncthreads();

  // ======== epilogue: +u*D, tanh-GELU, bf16 store ========
  float Dd = Dv[d];
  float vals[16];
  int base = 8*tid + (tid >> 1);
  #pragma unroll
  for (int i = 0; i < 8; ++i) {
    float2 q = lds[base + i];
    vals[2*i]   = q.x;
    vals[2*i+1] = q.y;
  }
  #pragma unroll
  for (int c = 0; c < 4; ++c) {
    float4 uu = uR4[tid*4 + c];
    vals[4*c+0] += uu.x * Dd;
    vals[4*c+1] += uu.y * Dd;
    vals[4*c+2] += uu.z * Dd;
    vals[4*c+3] += uu.w * Dd;
  }
  union { bf16 h[16]; uint4 q[2]; } st;
  #pragma unroll
  for (int i = 0; i < 16; ++i) {
    float x = vals[i];
    // gelu(x) ~= x * sigmoid(2q), q = 0.79788456(x + 0.044715 x^3); max err ~1e-3
    float x2 = x * x;
    float q = x * (0.7978845608f + 0.0356774081f * x2);
    float e = __expf(-2.0f * q);
    float g = x * __builtin_amdgcn_rcpf(1.0f + e);
    st.h[i] = (bf16)g;
  }
  uint4* outp = (uint4*)(ynat + (size_t)row * 4096 + tid * 16);
  outp[0] = st.q[0];
  outp[1] = st.q[1];
}

// ---------------------------------------------------------------------------
// Kernel 4: y [b][u][l] bf16 -> yT [(b,l)][u] bf16 (64x64 tiles via LDS)
// ---------------------------------------------------------------------------
__global__ __launch_bounds__(256) void transpose_kernel(const ushort* __restrict__ ynat,
                                                        ushort* __restrict__ yT)
{
  __shared__ ushort T[64 * 68];
  int tid = threadIdx.x;
  int l0 = blockIdx.x * 64;
  int u0 = blockIdx.y * 64;
  int b  = blockIdx.z;
  const ushort* src = ynat + ((size_t)(b*1024 + u0)) * 4096 + l0;
  #pragma unroll
  for (int it = 0; it < 4; ++it) {
    int c = tid + it*256;
    int r = c >> 4;
    int c4 = c & 15;
    ushort4 v = *(const ushort4*)(src + (size_t)r * 4096 + c4*4);
    *(ushort4*)&T[r*68 + c4*4] = v;
  }
  __syncthreads();
  ushort* dst = yT + ((size_t)(b*4096 + l0)) * 1024 + u0;
  #pragma unroll
  for (int it = 0; it < 4; ++it) {
    int c = tid + it*256;
    int lr = c >> 4;
    int u4 = c & 15;
    ushort4 v;
    v.x = T[(u4*4+0)*68 + lr];
    v.y = T[(u4*4+1)*68 + lr];
    v.z = T[(u4*4+2)*68 + lr];
    v.w = T[(u4*4+3)*68 + lr];
    *(ushort4*)(dst + (size_t)lr * 1024 + u4*4) = v;
  }
}

// ---------------------------------------------------------------------------
// Kernel 5: GEMM out[b][v][l] = sum_u Wbf[v][u] * yT[(b,l)][u] + bias[v]
// ---------------------------------------------------------------------------
#define GL_LDS16(g, l) __builtin_amdgcn_global_load_lds( \
    (const __attribute__((address_space(1))) void*)(g),  \
    (__attribute__((address_space(3))) void*)(l), 16, 0, 0)

__global__ __launch_bounds__(256) void gemm_kernel(
    const bf16* __restrict__ A,      // Wbf [v][u] 1024x1024
    const bf16* __restrict__ B,      // yT [(b,l)][u] 32768x1024
    const float* __restrict__ bias,
    float* __restrict__ out)
{
  __shared__ bf16 ldsA[128 * 32];
  __shared__ bf16 ldsB[128 * 32];
  int tid = threadIdx.x;
  int lane = tid & 63;
  int w = tid >> 6;
  int wm = w & 1, wn = w >> 1;
  int m0 = blockIdx.x * 128;
  int n0 = blockIdx.y * 128;
  int lrow = lane & 15;
  int quad = lane >> 4;
  f32x4 acc[4][4] = {};
  for (int kk0 = 0; kk0 < 1024; kk0 += 32) {
    __syncthreads();
    #pragma unroll
    for (int i = 0; i < 2; ++i) {
      int c = tid + 256*i;
      int row = c >> 2;
      int kc = c & 3;
      const bf16* ga = A + (size_t)(m0 + row) * 1024 + kk0 + kc*8;
      bf16* la = ldsA + (size_t)(w*64 + 256*i) * 8;
      GL_LDS16(ga, la);
      const bf16* gb = B + (size_t)(n0 + row) * 1024 + kk0 + kc*8;
      bf16* lb = ldsB + (size_t)(w*64 + 256*i) * 8;
      GL_LDS16(gb, lb);
    }
    __syncthreads();
    bf16x8 a[4], bq[4];
    #pragma unroll
    for (int mi = 0; mi < 4; ++mi)
      a[mi] = *(const bf16x8*)&ldsA[(wm*64 + mi*16 + lrow)*32 + quad*8];
    #pragma unroll
    for (int ni = 0; ni < 4; ++ni)
      bq[ni] = *(const bf16x8*)&ldsB[(wn*64 + ni*16 + lrow)*32 + quad*8];
    #pragma unroll
    for (int mi = 0; mi < 4; ++mi)
      #pragma unroll
      for (int ni = 0; ni < 4; ++ni)
        acc[mi][ni] = __builtin_amdgcn_mfma_f32_16x16x32_bf16(a[mi], bq[ni], acc[mi][ni], 0, 0, 0);
  }
  #pragma unroll
  for (int mi = 0; mi < 4; ++mi) {
    #pragma unroll
    for (int r = 0; r < 4; ++r) {
      int vrow = m0 + wm*64 + mi*16 + quad*4 + r;
      float bv = bias[vrow];
      #pragma unroll
      for (int ni = 0; ni < 4; ++ni) {
        int n = n0 + wn*64 + ni*16 + lrow;
        int bidx = n >> 12;
        int l = n & 4095;
        out[((size_t)bidx << 22) + ((size_t)vrow << 12) + l] = acc[mi][ni][r] + bv;
      }
    }
  }
}

// ---------------------------------------------------------------------------
// Workspace layout (bytes):
//   CFa  @ 0          : 1024*2048*8 = 16,777,216   (phase A)
//   CFb  @ 16,777,216 : 16,777,216                 (phase A)
//   CFd  @ 33,554,432 : 16,777,216  (ends 50,331,648, phase A)
//   yT   @ 0          : 67,108,864                 (phase B, aliases CF)
//   Wbf  @ 67,108,864 : 2,097,152
//   ynat @ 69,206,016 : 67,108,864   (total 136,314,880)
// ---------------------------------------------------------------------------
extern "C" void kernel_launch(void* const* d_in, const int* in_sizes, int n_in,
                              void* d_out, int out_size, void* d_ws, size_t ws_size,
                              hipStream_t stream)
{
  const float* u  = (const float*)d_in[0];
  const float* k0 = (const float*)d_in[1];
  const float* k1 = (const float*)d_in[2];
  const float* k2 = (const float*)d_in[3];
  const float* k3 = (const float*)d_in[4];
  const float* k4 = (const float*)d_in[5];
  const float* k5 = (const float*)d_in[6];
  const float* k6 = (const float*)d_in[7];
  const float* Dv = (const float*)d_in[8];
  const float* W  = (const float*)d_in[9];
  const float* bs = (const float*)d_in[10];
  float* out = (float*)d_out;

  char* ws = (char*)d_ws;
  float2* CFa = (float2*)(ws);
  float2* CFb = (float2*)(ws + 16777216);
  float2* CFd = (float2*)(ws + 33554432);
  bf16*  yT   = (bf16*)(ws);                 // aliases CF tables (dead by then)
  bf16*  Wbf  = (bf16*)(ws + 67108864);
  bf16*  ynat = (bf16*)(ws + 69206016);

  hipLaunchKernelGGL(prep_kf_kernel, dim3(1024), dim3(256), 65536, stream,
                     k0, k1, k2, k3, k4, k5, k6, CFa, CFb, CFd);
  hipLaunchKernelGGL(wcast_kernel, dim3(1024), dim3(256), 0, stream, W, Wbf);
  hipLaunchKernelGGL(fftconv_kernel, dim3(8192), dim3(256), 0, stream,
                     u, Dv, CFa, CFb, CFd, ynat);
  hipLaunchKernelGGL(transpose_kernel, dim3(64, 16, 8), dim3(256), 0, stream,
                     (const ushort*)ynat, (ushort*)yT);
  hipLaunchKernelGGL(gemm_kernel, dim3(8, 256), dim3(256), 0, stream, Wbf, yT, bs, out);
}